// Round 15
// baseline (462.113 us; speedup 1.0000x reference)
//
#include <hip/hip_runtime.h>
#include <math.h>

typedef __attribute__((ext_vector_type(8))) short short8;   // 8 bf16 (MFMA A/B frag)
typedef __attribute__((ext_vector_type(4))) float f32x4;    // MFMA acc frag
typedef __attribute__((ext_vector_type(2))) float f32x2;
typedef __attribute__((ext_vector_type(4))) unsigned u32x4;

#define PI_OVER_CUTOFF 0.31415926535897932f
#define SLOPE 0.015f

__device__ __forceinline__ unsigned short f2bf(float x) {
    unsigned u = __float_as_uint(x);
    return (unsigned short)((u + 0x7FFFu + ((u >> 16) & 1u)) >> 16);   // RNE
}
// packed f32x2 -> bf16x2, RNE, one instruction. D.lo = cvt(S0), D.hi = cvt(S1).
__device__ __forceinline__ unsigned cvt_pk_bf16(float lo, float hi) {
    unsigned r;
    asm("v_cvt_pk_bf16_f32 %0, %1, %2" : "=v"(r) : "v"(lo), "v"(hi));
    return r;
}
__device__ __forceinline__ short8 pack4(unsigned a, unsigned b, unsigned c, unsigned d) {
    u32x4 t = {a, b, c, d};
    return __builtin_bit_cast(short8, t);
}
// elementwise bf16 product of two bf16x8 frags, computed in f32, repacked bf16
__device__ __forceinline__ short8 mulbf8(short8 w, short8 v) {
    u32x4 uw = __builtin_bit_cast(u32x4, w);
    u32x4 uv = __builtin_bit_cast(u32x4, v);
    unsigned r0, r1, r2, r3;
#define MB(i, r)                                                         \
    {                                                                    \
        float wl = __uint_as_float(uw[i] << 16);                         \
        float wh = __uint_as_float(uw[i] & 0xFFFF0000u);                 \
        float vl = __uint_as_float(uv[i] << 16);                         \
        float vh = __uint_as_float(uv[i] & 0xFFFF0000u);                 \
        r = cvt_pk_bf16(wl * vl, wh * vh);                               \
    }
    MB(0, r0) MB(1, r1) MB(2, r2) MB(3, r3)
#undef MB
    return pack4(r0, r1, r2, r3);
}

// async global(per-lane) -> LDS(wave-uniform base, lane*16B) 16-byte copy
#define GLOAD_LDS16(g, l)                                                                      \
    __builtin_amdgcn_global_load_lds((const __attribute__((address_space(1))) unsigned*)(g),   \
                                     (__attribute__((address_space(3))) unsigned*)(l), 16, 0, 0)

// ---- kernel 0: weights -> bf16 (R14-exact) ------------------------------------
// w1p: [128][64] row-major, NOT swizzled (B-frag reads from global, L1-hot).
// wsrc: w2|w3|wo each [128][128], PRE-SWIZZLED: (c,k) at c*128 + (k ^ ((c&15)<<3))
//       -> linear global_load_lds + swizzled ds_read is conflict-free (R6-verified).
__global__ void prep_weights(const float* __restrict__ w1, const float* __restrict__ w2,
                             const float* __restrict__ w3, const float* __restrict__ wo,
                             unsigned short* __restrict__ w1p, unsigned short* __restrict__ wsrc) {
    int i = blockIdx.x * 256 + threadIdx.x;
    unsigned short* w2s = wsrc;
    unsigned short* w3s = wsrc + 128 * 128;
    unsigned short* wos = w3s + 128 * 128;
    if (i < 128 * 64) {
        int c = i >> 6, k = i & 63;
        w1p[i] = (k < 50) ? f2bf(w1[c * 50 + k]) : (unsigned short)0;  // pad K 50->64
    }
    if (i < 128 * 128) {
        int c = i >> 7, k = i & 127;
        int d = c * 128 + (k ^ ((c & 15) << 3));
        w2s[d] = f2bf(w2[i]);
        w3s[d] = f2bf(w3[i]);
        wos[d] = f2bf(wo[i] + ((c == k) ? 1.0f : 0.0f));  // fold "+e" residual
    }
}

// ---------------- kernel 1: vp = v @ lin_w.T  -> bf16 [N][128] -----------------
__global__ __launch_bounds__(256) void vp_gemm(const float* __restrict__ v,
                                               const float* __restrict__ lin_w,
                                               unsigned short* __restrict__ vp, int nnodes) {
    const int tid = threadIdx.x;
    const int lane = tid & 63;
    const int wv = tid >> 6;          // wave 0..3 -> col strip of 32
    const int l15 = lane & 15;
    const int l4 = lane >> 4;
    const int r0 = blockIdx.x * 64;
    const int c0 = wv * 32;

    f32x4 acc[4][2] = {};
#pragma unroll
    for (int kf = 0; kf < 4; ++kf) {
        short8 a[4];
#pragma unroll
        for (int mf = 0; mf < 4; ++mf) {
            int row = r0 + mf * 16 + l15;
            f32x4 x0 = {}, x1 = {};
            if (row < nnodes) {
                const float* p = v + (size_t)row * 128 + kf * 32 + l4 * 8;
                x0 = *reinterpret_cast<const f32x4*>(p);
                x1 = *reinterpret_cast<const f32x4*>(p + 4);
            }
            a[mf] = pack4(cvt_pk_bf16(x0[0], x0[1]), cvt_pk_bf16(x0[2], x0[3]),
                          cvt_pk_bf16(x1[0], x1[1]), cvt_pk_bf16(x1[2], x1[3]));
        }
        short8 b[2];
#pragma unroll
        for (int nf = 0; nf < 2; ++nf) {
            const float* p = lin_w + (size_t)(c0 + nf * 16 + l15) * 128 + kf * 32 + l4 * 8;
            f32x4 x0 = *reinterpret_cast<const f32x4*>(p);
            f32x4 x1 = *reinterpret_cast<const f32x4*>(p + 4);
            b[nf] = pack4(cvt_pk_bf16(x0[0], x0[1]), cvt_pk_bf16(x0[2], x0[3]),
                          cvt_pk_bf16(x1[0], x1[1]), cvt_pk_bf16(x1[2], x1[3]));
        }
#pragma unroll
        for (int mf = 0; mf < 4; ++mf)
#pragma unroll
            for (int nf = 0; nf < 2; ++nf)
                acc[mf][nf] = __builtin_amdgcn_mfma_f32_16x16x32_bf16(a[mf], b[nf], acc[mf][nf], 0, 0, 0);
    }
#pragma unroll
    for (int mf = 0; mf < 4; ++mf)
#pragma unroll
        for (int nf = 0; nf < 2; ++nf)
#pragma unroll
            for (int q = 0; q < 4; ++q) {
                int row = r0 + mf * 16 + l4 * 4 + q;
                if (row < nnodes)
                    vp[(size_t)row * 128 + c0 + nf * 16 + l15] = f2bf(acc[mf][nf][q]);
            }
}

// ---- kernel 2: M=48, 2 blocks/CU (R14) + staging-window overlap --------------
// R14 champion geometry (4 waves x 48 edges, 80KB LDS -> 2 independent blocks/CU,
// occupancy 22%, 452us). R15 delta: the two exposed single-buffer staging windows
// (w3 between bar2-bar3, wo between bar4-bar5) are now filled with the S2/S3
// epilogues (wave-private h writes need no barrier) + the dist/vp loads; biases
// hoisted to registers. Uses the ~130 spare VGPRs measured at R14 (VGPR=124).
__global__ __launch_bounds__(256, 2) void fused_edge(
    const float* __restrict__ dist, const float* __restrict__ dist_emb,
    const int* __restrict__ edge_index,
    const float* __restrict__ b1, const float* __restrict__ b2,
    const float* __restrict__ b3, const float* __restrict__ bo,
    const unsigned short* __restrict__ vp,
    const unsigned short* __restrict__ w1p, const unsigned short* __restrict__ wsrc,
    float* __restrict__ out, int E) {
    __shared__ __align__(16) unsigned short wbuf[16384];       // 32KB single buffer, swizzled
    __shared__ __align__(16) unsigned char lds_h[4][12288];    // per-wave [48][256B], swizzled

    const int tid = threadIdx.x;
    const int lane = tid & 63;
    const int wv = tid >> 6;
    const int l15 = lane & 15;
    const int l4 = lane >> 4;
    const long e0 = (long)blockIdx.x * 192 + wv * 48;
    const long eE = E;
    unsigned char* hb = lds_h[wv];
    const unsigned short* w2s = wsrc;
    const unsigned short* w3s = wsrc + 128 * 128;
    const unsigned short* wos = w3s + 128 * 128;

#define STAGE_W(src)                                                       \
    _Pragma("unroll")                                                      \
    for (int it = 0; it < 8; ++it) {                                       \
        int chunk = it * 4 + wv;                                           \
        GLOAD_LDS16((src) + chunk * 512 + lane * 8, &wbuf[chunk * 512]);   \
    }

    // issue w2 staging NOW; S1 (which doesn't touch wbuf) runs under it
    STAGE_W(w2s)

    // hoisted edge indices (clamped for the partial last block) + biases in regs
    int jm[3];
#pragma unroll
    for (int mf = 0; mf < 3; ++mf) {
        long er = e0 + mf * 16 + l15;
        if (er >= eE) er = eE - 1;
        jm[mf] = edge_index[er] * 128;
    }
    float bb1[8], bb2[8], bb3[8], bbo[8];
#pragma unroll
    for (int nf = 0; nf < 8; ++nf) {
        bb1[nf] = b1[nf * 16 + l15];
        bb2[nf] = b2[nf * 16 + l15];
        bb3[nf] = b3[nf * 16 + l15];
        bbo[nf] = bo[nf * 16 + l15];
    }

    f32x4 acc[3][8];

#define INIT_ACC(bb)                                                                \
    _Pragma("unroll")                                                               \
    for (int nf = 0; nf < 8; ++nf) {                                                \
        float b = (bb)[nf];                                                         \
        _Pragma("unroll")                                                           \
        for (int mf = 0; mf < 3; ++mf) acc[mf][nf] = (f32x4){b, b, b, b};           \
    }

#define EPILOGUE_TO_LDS()                                                           \
    _Pragma("unroll")                                                               \
    for (int mf = 0; mf < 3; ++mf)                                                  \
        _Pragma("unroll")                                                           \
        for (int nf = 0; nf < 8; ++nf) {                                            \
            f32x4 vv = acc[mf][nf];                                                 \
            _Pragma("unroll")                                                       \
            for (int q = 0; q < 4; ++q) vv[q] = fmaxf(vv[q], SLOPE * vv[q]);        \
            unsigned p01 = cvt_pk_bf16(vv[0], vv[1]);                               \
            unsigned p23 = cvt_pk_bf16(vv[2], vv[3]);                               \
            int col2 = (nf * 16 + l15) * 2;                                         \
            int rb = mf * 16 + l4 * 4;                                              \
            *(unsigned short*)(hb + (rb + 0) * 256 + (col2 ^ ((l4 * 4 + 0) << 4))) = (unsigned short)p01;         \
            *(unsigned short*)(hb + (rb + 1) * 256 + (col2 ^ ((l4 * 4 + 1) << 4))) = (unsigned short)(p01 >> 16); \
            *(unsigned short*)(hb + (rb + 2) * 256 + (col2 ^ ((l4 * 4 + 2) << 4))) = (unsigned short)p23;         \
            *(unsigned short*)(hb + (rb + 3) * 256 + (col2 ^ ((l4 * 4 + 3) << 4))) = (unsigned short)(p23 >> 16); \
        }

#define HB_READ(mf, kf) \
    (*reinterpret_cast<const short8*>(hb + ((mf) * 16 + l15) * 256 + (((kf) * 64 + l4 * 16) ^ (l15 << 4))))
#define WB_READ(nf, kf) \
    (*reinterpret_cast<const short8*>(&wbuf[((nf) * 16 + l15) * 128 + (((kf) * 32 + l4 * 8) ^ (l15 << 3))]))

    // ===== stage 1: h1 = leaky(emb @ w1.T + b1)  [w1 B-frags from global] =====
    INIT_ACC(bb1)
#pragma unroll
    for (int kf = 0; kf < 2; ++kf) {
        short8 a[3];
#pragma unroll
        for (int mf = 0; mf < 3; ++mf) {
            long er = e0 + mf * 16 + l15;
            if (er >= eE) er = eE - 1;
            const float* src = dist_emb + er * 50 + kf * 32 + l4 * 8;
            unsigned pk[4];
#pragma unroll
            for (int p = 0; p < 4; ++p) {
                int k2 = kf * 32 + l4 * 8 + 2 * p;
                f32x2 x = (k2 < 50) ? *reinterpret_cast<const f32x2*>(src + 2 * p)
                                    : (f32x2){0.f, 0.f};
                pk[p] = cvt_pk_bf16(x[0], x[1]);
            }
            a[mf] = pack4(pk[0], pk[1], pk[2], pk[3]);
        }
#pragma unroll
        for (int nf = 0; nf < 8; ++nf) {
            short8 b = *reinterpret_cast<const short8*>(w1p + (nf * 16 + l15) * 64 + kf * 32 + l4 * 8);
#pragma unroll
            for (int mf = 0; mf < 3; ++mf)
                acc[mf][nf] = __builtin_amdgcn_mfma_f32_16x16x32_bf16(a[mf], b, acc[mf][nf], 0, 0, 0);
        }
    }
    EPILOGUE_TO_LDS()

    __syncthreads();   // bar1: w2 staged (vmcnt drained)

    // ===== stage 2 MFMA: h1 @ w2.T =====
    INIT_ACC(bb2)
#pragma unroll
    for (int kf = 0; kf < 4; ++kf) {
        short8 a[3];
#pragma unroll
        for (int mf = 0; mf < 3; ++mf) a[mf] = HB_READ(mf, kf);
#pragma unroll
        for (int nf = 0; nf < 8; ++nf) {
            short8 b = WB_READ(nf, kf);
#pragma unroll
            for (int mf = 0; mf < 3; ++mf)
                acc[mf][nf] = __builtin_amdgcn_mfma_f32_16x16x32_bf16(a[mf], b, acc[mf][nf], 0, 0, 0);
        }
    }

    __syncthreads();   // bar2: all waves done reading w2
    STAGE_W(w3s)       // w3 staging issued; hidden under the work below

    EPILOGUE_TO_LDS()  // S2 epilogue (wave-private h) fills the staging window

    // dist + first vp slice: issued in the window, consumed after bar4 / in S4
    float dd[3][4];
#pragma unroll
    for (int mf = 0; mf < 3; ++mf)
#pragma unroll
        for (int q = 0; q < 4; ++q) {
            long dr = e0 + mf * 16 + l4 * 4 + q;
            if (dr >= eE) dr = eE - 1;
            dd[mf][q] = dist[dr];
        }
    short8 vcur[3];
#pragma unroll
    for (int mf = 0; mf < 3; ++mf)
        vcur[mf] = *reinterpret_cast<const short8*>(vp + jm[mf] + l4 * 8);

    __syncthreads();   // bar3: w3 staged

    // ===== stage 3 MFMA: h2 @ w3.T =====
    INIT_ACC(bb3)
#pragma unroll
    for (int kf = 0; kf < 4; ++kf) {
        short8 a[3];
#pragma unroll
        for (int mf = 0; mf < 3; ++mf) a[mf] = HB_READ(mf, kf);
#pragma unroll
        for (int nf = 0; nf < 8; ++nf) {
            short8 b = WB_READ(nf, kf);
#pragma unroll
            for (int mf = 0; mf < 3; ++mf)
                acc[mf][nf] = __builtin_amdgcn_mfma_f32_16x16x32_bf16(a[mf], b, acc[mf][nf], 0, 0, 0);
        }
    }

    __syncthreads();   // bar4: all waves done reading w3
    STAGE_W(wos)       // wo staging issued; hidden under the S3 epilogue below

    // S3 epilogue: W = (acc) * C(dist) -> h  (cos + scale + wave-private writes)
    {
        float Cw[3][4];
#pragma unroll
        for (int mf = 0; mf < 3; ++mf)
#pragma unroll
            for (int q = 0; q < 4; ++q)
                Cw[mf][q] = 0.5f * (__cosf(dd[mf][q] * PI_OVER_CUTOFF) + 1.0f);
#pragma unroll
        for (int mf = 0; mf < 3; ++mf)
#pragma unroll
            for (int nf = 0; nf < 8; ++nf) {
                f32x4 vv = acc[mf][nf];
#pragma unroll
                for (int q = 0; q < 4; ++q) vv[q] = vv[q] * Cw[mf][q];
                unsigned p01 = cvt_pk_bf16(vv[0], vv[1]);
                unsigned p23 = cvt_pk_bf16(vv[2], vv[3]);
                int col2 = (nf * 16 + l15) * 2;
                int rb = mf * 16 + l4 * 4;
                *(unsigned short*)(hb + (rb + 0) * 256 + (col2 ^ ((l4 * 4 + 0) << 4))) = (unsigned short)p01;
                *(unsigned short*)(hb + (rb + 1) * 256 + (col2 ^ ((l4 * 4 + 1) << 4))) = (unsigned short)(p01 >> 16);
                *(unsigned short*)(hb + (rb + 2) * 256 + (col2 ^ ((l4 * 4 + 2) << 4))) = (unsigned short)p23;
                *(unsigned short*)(hb + (rb + 3) * 256 + (col2 ^ ((l4 * 4 + 3) << 4))) = (unsigned short)(p23 >> 16);
            }
    }

    __syncthreads();   // bar5: wo staged

    // ===== stage 4: out = (vp[j] .* W) @ (wo + I).T + bo  [vp streamed] =====
    INIT_ACC(bbo)
#pragma unroll
    for (int kf = 0; kf < 4; ++kf) {
        short8 vnxt[3];
        if (kf < 3) {
#pragma unroll
            for (int mf = 0; mf < 3; ++mf)
                vnxt[mf] = *reinterpret_cast<const short8*>(vp + jm[mf] + (kf + 1) * 32 + l4 * 8);
        }
        short8 a[3];
#pragma unroll
        for (int mf = 0; mf < 3; ++mf) a[mf] = mulbf8(HB_READ(mf, kf), vcur[mf]);
#pragma unroll
        for (int nf = 0; nf < 8; ++nf) {
            short8 b = WB_READ(nf, kf);
#pragma unroll
            for (int mf = 0; mf < 3; ++mf)
                acc[mf][nf] = __builtin_amdgcn_mfma_f32_16x16x32_bf16(a[mf], b, acc[mf][nf], 0, 0, 0);
        }
#pragma unroll
        for (int mf = 0; mf < 3; ++mf) vcur[mf] = vnxt[mf];
    }
#pragma unroll
    for (int mf = 0; mf < 3; ++mf)
#pragma unroll
        for (int q = 0; q < 4; ++q) {
            long row = e0 + mf * 16 + l4 * 4 + q;
            if (row < eE) {
                float* op = out + row * 128 + l15;
#pragma unroll
                for (int nf = 0; nf < 8; ++nf)
                    op[nf * 16] = acc[mf][nf][q];
            }
        }
#undef EPILOGUE_TO_LDS
#undef INIT_ACC
#undef HB_READ
#undef WB_READ
#undef STAGE_W
}

extern "C" void kernel_launch(void* const* d_in, const int* in_sizes, int n_in,
                              void* d_out, int out_size, void* d_ws, size_t ws_size,
                              hipStream_t stream) {
    const float* v        = (const float*)d_in[0];
    const float* dist     = (const float*)d_in[1];
    const float* dist_emb = (const float*)d_in[2];
    const int*   edge_idx = (const int*)d_in[3];
    const float* lin_w    = (const float*)d_in[4];
    const float* w1 = (const float*)d_in[5];
    const float* b1 = (const float*)d_in[6];
    const float* w2 = (const float*)d_in[7];
    const float* b2 = (const float*)d_in[8];
    const float* w3 = (const float*)d_in[9];
    const float* b3 = (const float*)d_in[10];
    const float* wo = (const float*)d_in[11];
    const float* bo = (const float*)d_in[12];
    float* out = (float*)d_out;

    const int nnodes = in_sizes[0] / 128;   // 50000
    const int E = in_sizes[1];              // 1600000
    const int ntiles = (E + 191) / 192;     // 192 edges per block (M=48 x 4 waves)

    unsigned short* vp   = (unsigned short*)d_ws;           // [nnodes][128] bf16
    unsigned short* w1p  = vp + (size_t)nnodes * 128;       // [128][64] row-major
    unsigned short* wsrc = w1p + 128 * 64;                  // 3x[128][128] swizzled

    prep_weights<<<64, 256, 0, stream>>>(w1, w2, w3, wo, w1p, wsrc);
    vp_gemm<<<(nnodes + 63) / 64, 256, 0, stream>>>(v, lin_w, vp, nnodes);
    fused_edge<<<ntiles, 256, 0, stream>>>(dist, dist_emb, edge_idx,
                                           b1, b2, b3, bo, vp, w1p, wsrc, out, E);
}

// Round 16
// 453.034 us; speedup vs baseline: 1.0200x; 1.0200x over previous
//
#include <hip/hip_runtime.h>
#include <math.h>

typedef __attribute__((ext_vector_type(8))) short short8;   // 8 bf16 (MFMA A/B frag)
typedef __attribute__((ext_vector_type(4))) float f32x4;    // MFMA acc frag
typedef __attribute__((ext_vector_type(2))) float f32x2;
typedef __attribute__((ext_vector_type(4))) unsigned u32x4;

#define PI_OVER_CUTOFF 0.31415926535897932f
#define SLOPE 0.015f

__device__ __forceinline__ unsigned short f2bf(float x) {
    unsigned u = __float_as_uint(x);
    return (unsigned short)((u + 0x7FFFu + ((u >> 16) & 1u)) >> 16);   // RNE
}
// packed f32x2 -> bf16x2, RNE, one instruction. D.lo = cvt(S0), D.hi = cvt(S1).
__device__ __forceinline__ unsigned cvt_pk_bf16(float lo, float hi) {
    unsigned r;
    asm("v_cvt_pk_bf16_f32 %0, %1, %2" : "=v"(r) : "v"(lo), "v"(hi));
    return r;
}
__device__ __forceinline__ short8 pack4(unsigned a, unsigned b, unsigned c, unsigned d) {
    u32x4 t = {a, b, c, d};
    return __builtin_bit_cast(short8, t);
}
// elementwise bf16 product of two bf16x8 frags, computed in f32, repacked bf16
__device__ __forceinline__ short8 mulbf8(short8 w, short8 v) {
    u32x4 uw = __builtin_bit_cast(u32x4, w);
    u32x4 uv = __builtin_bit_cast(u32x4, v);
    unsigned r0, r1, r2, r3;
#define MB(i, r)                                                         \
    {                                                                    \
        float wl = __uint_as_float(uw[i] << 16);                         \
        float wh = __uint_as_float(uw[i] & 0xFFFF0000u);                 \
        float vl = __uint_as_float(uv[i] << 16);                         \
        float vh = __uint_as_float(uv[i] & 0xFFFF0000u);                 \
        r = cvt_pk_bf16(wl * vl, wh * vh);                               \
    }
    MB(0, r0) MB(1, r1) MB(2, r2) MB(3, r3)
#undef MB
    return pack4(r0, r1, r2, r3);
}

// async global(per-lane) -> LDS(wave-uniform base, lane*16B) 16-byte copy
#define GLOAD_LDS16(g, l)                                                                      \
    __builtin_amdgcn_global_load_lds((const __attribute__((address_space(1))) unsigned*)(g),   \
                                     (__attribute__((address_space(3))) unsigned*)(l), 16, 0, 0)

// ---- kernel 0: weights -> bf16 ------------------------------------------------
// w1p: [128][64] row-major, NOT swizzled (B-frag reads from global, L1-hot).
// wsrc: w2|w3|wo each [128][128], PRE-SWIZZLED: (c,k) at c*128 + (k ^ ((c&15)<<3))
//       -> linear global_load_lds + swizzled ds_read is conflict-free (R6-verified).
__global__ void prep_weights(const float* __restrict__ w1, const float* __restrict__ w2,
                             const float* __restrict__ w3, const float* __restrict__ wo,
                             unsigned short* __restrict__ w1p, unsigned short* __restrict__ wsrc) {
    int i = blockIdx.x * 256 + threadIdx.x;
    unsigned short* w2s = wsrc;
    unsigned short* w3s = wsrc + 128 * 128;
    unsigned short* wos = w3s + 128 * 128;
    if (i < 128 * 64) {
        int c = i >> 6, k = i & 63;
        w1p[i] = (k < 50) ? f2bf(w1[c * 50 + k]) : (unsigned short)0;  // pad K 50->64
    }
    if (i < 128 * 128) {
        int c = i >> 7, k = i & 127;
        int d = c * 128 + (k ^ ((c & 15) << 3));
        w2s[d] = f2bf(w2[i]);
        w3s[d] = f2bf(w3[i]);
        wos[d] = f2bf(wo[i] + ((c == k) ? 1.0f : 0.0f));  // fold "+e" residual
    }
}

// ---------------- kernel 1: vp = v @ lin_w.T  -> bf16 [N][128] -----------------
__global__ __launch_bounds__(256) void vp_gemm(const float* __restrict__ v,
                                               const float* __restrict__ lin_w,
                                               unsigned short* __restrict__ vp, int nnodes) {
    const int tid = threadIdx.x;
    const int lane = tid & 63;
    const int wv = tid >> 6;          // wave 0..3 -> col strip of 32
    const int l15 = lane & 15;
    const int l4 = lane >> 4;
    const int r0 = blockIdx.x * 64;
    const int c0 = wv * 32;

    f32x4 acc[4][2] = {};
#pragma unroll
    for (int kf = 0; kf < 4; ++kf) {
        short8 a[4];
#pragma unroll
        for (int mf = 0; mf < 4; ++mf) {
            int row = r0 + mf * 16 + l15;
            f32x4 x0 = {}, x1 = {};
            if (row < nnodes) {
                const float* p = v + (size_t)row * 128 + kf * 32 + l4 * 8;
                x0 = *reinterpret_cast<const f32x4*>(p);
                x1 = *reinterpret_cast<const f32x4*>(p + 4);
            }
            a[mf] = pack4(cvt_pk_bf16(x0[0], x0[1]), cvt_pk_bf16(x0[2], x0[3]),
                          cvt_pk_bf16(x1[0], x1[1]), cvt_pk_bf16(x1[2], x1[3]));
        }
        short8 b[2];
#pragma unroll
        for (int nf = 0; nf < 2; ++nf) {
            const float* p = lin_w + (size_t)(c0 + nf * 16 + l15) * 128 + kf * 32 + l4 * 8;
            f32x4 x0 = *reinterpret_cast<const f32x4*>(p);
            f32x4 x1 = *reinterpret_cast<const f32x4*>(p + 4);
            b[nf] = pack4(cvt_pk_bf16(x0[0], x0[1]), cvt_pk_bf16(x0[2], x0[3]),
                          cvt_pk_bf16(x1[0], x1[1]), cvt_pk_bf16(x1[2], x1[3]));
        }
#pragma unroll
        for (int mf = 0; mf < 4; ++mf)
#pragma unroll
            for (int nf = 0; nf < 2; ++nf)
                acc[mf][nf] = __builtin_amdgcn_mfma_f32_16x16x32_bf16(a[mf], b[nf], acc[mf][nf], 0, 0, 0);
    }
#pragma unroll
    for (int mf = 0; mf < 4; ++mf)
#pragma unroll
        for (int nf = 0; nf < 2; ++nf)
#pragma unroll
            for (int q = 0; q < 4; ++q) {
                int row = r0 + mf * 16 + l4 * 4 + q;
                if (row < nnodes)
                    vp[(size_t)row * 128 + c0 + nf * 16 + l15] = f2bf(acc[mf][nf][q]);
            }
}

// ---- kernel 2: THE R14 CHAMPION (452us) --------------------------------------
// M=48/wave, 4 waves, 80KB LDS (h 4x12KB + single 32KB wbuf) -> 2 INDEPENDENT
// blocks co-resident per CU (occupancy 22%): the sibling block's MFMA stream
// hides this block's barriers/staging/LDS-chain stalls. launch_bounds(256,2),
// VGPR 124, no spill; traffic clean (FETCH 391MB, WRITE 800MB = output only);
// 0 bank conflicts. Session map: M=64/1-block (R6 527us) < M=48/2-block (R14
// 452us); persistence, same-block TLP, intra-wave pipelining, barrier removal,
// staging-window overlap (R15) all measured worse. Remaining gap to the 190us
// HBM floor is dependent-chain latency needing asm-level counted-vmcnt
// pipelining -- beyond source-level HIP restructuring.
__global__ __launch_bounds__(256, 2) void fused_edge(
    const float* __restrict__ dist, const float* __restrict__ dist_emb,
    const int* __restrict__ edge_index,
    const float* __restrict__ b1, const float* __restrict__ b2,
    const float* __restrict__ b3, const float* __restrict__ bo,
    const unsigned short* __restrict__ vp,
    const unsigned short* __restrict__ w1p, const unsigned short* __restrict__ wsrc,
    float* __restrict__ out, int E) {
    __shared__ __align__(16) unsigned short wbuf[16384];       // 32KB single buffer, swizzled
    __shared__ __align__(16) unsigned char lds_h[4][12288];    // per-wave [48][256B], swizzled

    const int tid = threadIdx.x;
    const int lane = tid & 63;
    const int wv = tid >> 6;
    const int l15 = lane & 15;
    const int l4 = lane >> 4;
    const long e0 = (long)blockIdx.x * 192 + wv * 48;
    const long eE = E;
    unsigned char* hb = lds_h[wv];
    const unsigned short* w2s = wsrc;
    const unsigned short* w3s = wsrc + 128 * 128;
    const unsigned short* wos = w3s + 128 * 128;

#define STAGE_W(src)                                                       \
    _Pragma("unroll")                                                      \
    for (int it = 0; it < 8; ++it) {                                       \
        int chunk = it * 4 + wv;                                           \
        GLOAD_LDS16((src) + chunk * 512 + lane * 8, &wbuf[chunk * 512]);   \
    }

    // issue w2 staging NOW; S1 (which doesn't touch wbuf) runs under it
    STAGE_W(w2s)

    // hoisted edge indices (clamped for the partial last block)
    int jm[3];
#pragma unroll
    for (int mf = 0; mf < 3; ++mf) {
        long er = e0 + mf * 16 + l15;
        if (er >= eE) er = eE - 1;
        jm[mf] = edge_index[er] * 128;
    }

    f32x4 acc[3][8];

#define INIT_ACC(bp)                                                                \
    _Pragma("unroll")                                                               \
    for (int nf = 0; nf < 8; ++nf) {                                                \
        float b = (bp)[nf * 16 + l15];                                              \
        _Pragma("unroll")                                                           \
        for (int mf = 0; mf < 3; ++mf) acc[mf][nf] = (f32x4){b, b, b, b};           \
    }

#define EPILOGUE_TO_LDS()                                                           \
    _Pragma("unroll")                                                               \
    for (int mf = 0; mf < 3; ++mf)                                                  \
        _Pragma("unroll")                                                           \
        for (int nf = 0; nf < 8; ++nf) {                                            \
            f32x4 vv = acc[mf][nf];                                                 \
            _Pragma("unroll")                                                       \
            for (int q = 0; q < 4; ++q) vv[q] = fmaxf(vv[q], SLOPE * vv[q]);        \
            unsigned p01 = cvt_pk_bf16(vv[0], vv[1]);                               \
            unsigned p23 = cvt_pk_bf16(vv[2], vv[3]);                               \
            int col2 = (nf * 16 + l15) * 2;                                         \
            int rb = mf * 16 + l4 * 4;                                              \
            *(unsigned short*)(hb + (rb + 0) * 256 + (col2 ^ ((l4 * 4 + 0) << 4))) = (unsigned short)p01;         \
            *(unsigned short*)(hb + (rb + 1) * 256 + (col2 ^ ((l4 * 4 + 1) << 4))) = (unsigned short)(p01 >> 16); \
            *(unsigned short*)(hb + (rb + 2) * 256 + (col2 ^ ((l4 * 4 + 2) << 4))) = (unsigned short)p23;         \
            *(unsigned short*)(hb + (rb + 3) * 256 + (col2 ^ ((l4 * 4 + 3) << 4))) = (unsigned short)(p23 >> 16); \
        }

#define HB_READ(mf, kf) \
    (*reinterpret_cast<const short8*>(hb + ((mf) * 16 + l15) * 256 + (((kf) * 64 + l4 * 16) ^ (l15 << 4))))
#define WB_READ(nf, kf) \
    (*reinterpret_cast<const short8*>(&wbuf[((nf) * 16 + l15) * 128 + (((kf) * 32 + l4 * 8) ^ (l15 << 3))]))

    // ===== stage 1: h1 = leaky(emb @ w1.T + b1)  [w1 B-frags from global] =====
    INIT_ACC(b1)
#pragma unroll
    for (int kf = 0; kf < 2; ++kf) {
        short8 a[3];
#pragma unroll
        for (int mf = 0; mf < 3; ++mf) {
            long er = e0 + mf * 16 + l15;
            if (er >= eE) er = eE - 1;
            const float* src = dist_emb + er * 50 + kf * 32 + l4 * 8;
            unsigned pk[4];
#pragma unroll
            for (int p = 0; p < 4; ++p) {
                int k2 = kf * 32 + l4 * 8 + 2 * p;
                f32x2 x = (k2 < 50) ? *reinterpret_cast<const f32x2*>(src + 2 * p)
                                    : (f32x2){0.f, 0.f};
                pk[p] = cvt_pk_bf16(x[0], x[1]);
            }
            a[mf] = pack4(pk[0], pk[1], pk[2], pk[3]);
        }
#pragma unroll
        for (int nf = 0; nf < 8; ++nf) {
            short8 b = *reinterpret_cast<const short8*>(w1p + (nf * 16 + l15) * 64 + kf * 32 + l4 * 8);
#pragma unroll
            for (int mf = 0; mf < 3; ++mf)
                acc[mf][nf] = __builtin_amdgcn_mfma_f32_16x16x32_bf16(a[mf], b, acc[mf][nf], 0, 0, 0);
        }
    }
    EPILOGUE_TO_LDS()

    __syncthreads();   // bar1: w2 staged (vmcnt drained)

    // ===== stage 2: h2 = leaky(h1 @ w2.T + b2) =====
    INIT_ACC(b2)
#pragma unroll
    for (int kf = 0; kf < 4; ++kf) {
        short8 a[3];
#pragma unroll
        for (int mf = 0; mf < 3; ++mf) a[mf] = HB_READ(mf, kf);
#pragma unroll
        for (int nf = 0; nf < 8; ++nf) {
            short8 b = WB_READ(nf, kf);
#pragma unroll
            for (int mf = 0; mf < 3; ++mf)
                acc[mf][nf] = __builtin_amdgcn_mfma_f32_16x16x32_bf16(a[mf], b, acc[mf][nf], 0, 0, 0);
        }
    }
    EPILOGUE_TO_LDS()

    __syncthreads();   // bar2: all waves done reading w2
    STAGE_W(w3s)
    __syncthreads();   // bar3: w3 staged

    // ===== stage 3: W = (h2 @ w3.T + b3) * C(dist) =====
    {
        // dist + first vp slice issued at top (consumed at epilogue / stage 4)
        float dd[3][4];
#pragma unroll
        for (int mf = 0; mf < 3; ++mf)
#pragma unroll
            for (int q = 0; q < 4; ++q) {
                long dr = e0 + mf * 16 + l4 * 4 + q;
                if (dr >= eE) dr = eE - 1;
                dd[mf][q] = dist[dr];
            }
        short8 vcur[3];
#pragma unroll
        for (int mf = 0; mf < 3; ++mf)
            vcur[mf] = *reinterpret_cast<const short8*>(vp + jm[mf] + l4 * 8);

        INIT_ACC(b3)
#pragma unroll
        for (int kf = 0; kf < 4; ++kf) {
            short8 a[3];
#pragma unroll
            for (int mf = 0; mf < 3; ++mf) a[mf] = HB_READ(mf, kf);
#pragma unroll
            for (int nf = 0; nf < 8; ++nf) {
                short8 b = WB_READ(nf, kf);
#pragma unroll
                for (int mf = 0; mf < 3; ++mf)
                    acc[mf][nf] = __builtin_amdgcn_mfma_f32_16x16x32_bf16(a[mf], b, acc[mf][nf], 0, 0, 0);
            }
        }
        float Cw[3][4];
#pragma unroll
        for (int mf = 0; mf < 3; ++mf)
#pragma unroll
            for (int q = 0; q < 4; ++q)
                Cw[mf][q] = 0.5f * (__cosf(dd[mf][q] * PI_OVER_CUTOFF) + 1.0f);
#pragma unroll
        for (int mf = 0; mf < 3; ++mf)
#pragma unroll
            for (int nf = 0; nf < 8; ++nf) {
                f32x4 vv = acc[mf][nf];
#pragma unroll
                for (int q = 0; q < 4; ++q) vv[q] = vv[q] * Cw[mf][q];
                unsigned p01 = cvt_pk_bf16(vv[0], vv[1]);
                unsigned p23 = cvt_pk_bf16(vv[2], vv[3]);
                int col2 = (nf * 16 + l15) * 2;
                int rb = mf * 16 + l4 * 4;
                *(unsigned short*)(hb + (rb + 0) * 256 + (col2 ^ ((l4 * 4 + 0) << 4))) = (unsigned short)p01;
                *(unsigned short*)(hb + (rb + 1) * 256 + (col2 ^ ((l4 * 4 + 1) << 4))) = (unsigned short)(p01 >> 16);
                *(unsigned short*)(hb + (rb + 2) * 256 + (col2 ^ ((l4 * 4 + 2) << 4))) = (unsigned short)p23;
                *(unsigned short*)(hb + (rb + 3) * 256 + (col2 ^ ((l4 * 4 + 3) << 4))) = (unsigned short)(p23 >> 16);
            }

        __syncthreads();   // bar4: all waves done reading w3
        STAGE_W(wos)
        __syncthreads();   // bar5: wo staged

        // ===== stage 4: out = (vp[j] .* W) @ (wo + I).T + bo  [vp streamed] =====
        INIT_ACC(bo)
#pragma unroll
        for (int kf = 0; kf < 4; ++kf) {
            short8 vnxt[3];
            if (kf < 3) {
#pragma unroll
                for (int mf = 0; mf < 3; ++mf)
                    vnxt[mf] = *reinterpret_cast<const short8*>(vp + jm[mf] + (kf + 1) * 32 + l4 * 8);
            }
            short8 a[3];
#pragma unroll
            for (int mf = 0; mf < 3; ++mf) a[mf] = mulbf8(HB_READ(mf, kf), vcur[mf]);
#pragma unroll
            for (int nf = 0; nf < 8; ++nf) {
                short8 b = WB_READ(nf, kf);
#pragma unroll
                for (int mf = 0; mf < 3; ++mf)
                    acc[mf][nf] = __builtin_amdgcn_mfma_f32_16x16x32_bf16(a[mf], b, acc[mf][nf], 0, 0, 0);
            }
#pragma unroll
            for (int mf = 0; mf < 3; ++mf) vcur[mf] = vnxt[mf];
        }
#pragma unroll
        for (int mf = 0; mf < 3; ++mf)
#pragma unroll
            for (int q = 0; q < 4; ++q) {
                long row = e0 + mf * 16 + l4 * 4 + q;
                if (row < eE) {
                    float* op = out + row * 128 + l15;
#pragma unroll
                    for (int nf = 0; nf < 8; ++nf)
                        op[nf * 16] = acc[mf][nf][q];
                }
            }
    }
#undef EPILOGUE_TO_LDS
#undef INIT_ACC
#undef HB_READ
#undef WB_READ
#undef STAGE_W
}

extern "C" void kernel_launch(void* const* d_in, const int* in_sizes, int n_in,
                              void* d_out, int out_size, void* d_ws, size_t ws_size,
                              hipStream_t stream) {
    const float* v        = (const float*)d_in[0];
    const float* dist     = (const float*)d_in[1];
    const float* dist_emb = (const float*)d_in[2];
    const int*   edge_idx = (const int*)d_in[3];
    const float* lin_w    = (const float*)d_in[4];
    const float* w1 = (const float*)d_in[5];
    const float* b1 = (const float*)d_in[6];
    const float* w2 = (const float*)d_in[7];
    const float* b2 = (const float*)d_in[8];
    const float* w3 = (const float*)d_in[9];
    const float* b3 = (const float*)d_in[10];
    const float* wo = (const float*)d_in[11];
    const float* bo = (const float*)d_in[12];
    float* out = (float*)d_out;

    const int nnodes = in_sizes[0] / 128;   // 50000
    const int E = in_sizes[1];              // 1600000
    const int ntiles = (E + 191) / 192;     // 192 edges per block (M=48 x 4 waves)

    unsigned short* vp   = (unsigned short*)d_ws;           // [nnodes][128] bf16
    unsigned short* w1p  = vp + (size_t)nnodes * 128;       // [128][64] row-major
    unsigned short* wsrc = w1p + 128 * 64;                  // 3x[128][128] swizzled

    prep_weights<<<64, 256, 0, stream>>>(w1, w2, w3, wo, w1p, wsrc);
    vp_gemm<<<(nnodes + 63) / 64, 256, 0, stream>>>(v, lin_w, vp, nnodes);
    fused_edge<<<ntiles, 256, 0, stream>>>(dist, dist_emb, edge_idx,
                                           b1, b2, b3, bo, vp, w1p, wsrc, out, E);
}